// Round 12
// baseline (114.706 us; speedup 1.0000x reference)
//
#include <hip/hip_runtime.h>
#include <hip/hip_bf16.h>

#define NL 16
#define HID 16
#define LAT 64
#define BATCHN 262144
#define LSTRIDE 12288   /* bytes per layer fragment block */

typedef __attribute__((ext_vector_type(4))) float f32x4;
typedef __attribute__((ext_vector_type(8))) short b16x8;

// gfx950-verified MFMA (guide §3 / m89): lane 16g+c holds A[row=c][k=8g+j],
// B[k=8g+j][col=c]; D reg j = D[row=4g+j][col=c].
__device__ __forceinline__ f32x4 MFMA32(b16x8 a, b16x8 b, f32x4 c) {
  return __builtin_amdgcn_mfma_f32_16x16x32_bf16(a, b, c, 0, 0, 0);
}

// RNE pair-pack via the official intrinsic (round 9: passed, no asm hazards)
__device__ __forceinline__ unsigned pk2(float lo, float hi) {
  __hip_bfloat162 h2 = __float22bfloat162_rn(float2{lo, hi});
  union { __hip_bfloat162 h; unsigned u; } u; u.h = h2; return u.u;
}

#if __has_builtin(__builtin_amdgcn_exp2f)
__device__ __forceinline__ float fexp2(float x) { return __builtin_amdgcn_exp2f(x); }
#else
__device__ __forceinline__ float fexp2(float x) { return __expf(0.6931471805599453f * x); }
#endif
#if __has_builtin(__builtin_amdgcn_rcpf)
__device__ __forceinline__ float frcp(float x) { return __builtin_amdgcn_rcpf(x); }
#else
__device__ __forceinline__ float frcp(float x) { return __fdividef(1.f, x); }
#endif

__device__ __forceinline__ short bfs(float f) {
  union { __hip_bfloat16 h; short s; } u; u.h = __float2bfloat16(f); return u.s;
}
__device__ __forceinline__ float leaky(float v) { return fmaxf(v, 0.01f * v); }
#define TWO_LOG2E 2.885390081777927f   /* 2/ln2 = 2*log2(e) */
#define LOG2E     1.442695040888963f

// ---------------- setup: bake fragments into interleaved per-layer blocks ----------
// Layer block layout (1 KB slots, per-lane 16 B):
//  0:A1S 1:A1T 2:B1S 3:B1T | 4:A2S0 5:A2S1 6:A2T0 7:A2T1 | 8:C2S0 9:C2S1 10:C2T0 11:C2T1
// s-net GEMM2 fragments (A2S, C2S) PRE-SCALED by 2*log2(e): w = exp2(ds) directly.
__global__ void prep_frags(
    const float* __restrict__ sW1, const float* __restrict__ sb1,
    const float* __restrict__ sW2, const float* __restrict__ sb2,
    const float* __restrict__ tW1, const float* __restrict__ tb1,
    const float* __restrict__ tW2, const float* __restrict__ tb2,
    char* __restrict__ ws)
{
  const int l = blockIdx.x;
  const int lane = threadIdx.x;
  const int c = lane & 15, g = lane >> 4;
  const int PR = l & 1, PW = 1 - PR;
  char* base = ws + (size_t)l * LSTRIDE + lane * 16;

  b16x8 a;
  const float* w = sW1 + (l * HID + c) * LAT;
#pragma unroll
  for (int u = 0; u < 8; ++u) a[u] = bfs(w[16 * g + 2 * u + PR]);
  *(b16x8*)(base) = a;
  w = tW1 + (l * HID + c) * LAT;
#pragma unroll
  for (int u = 0; u < 8; ++u) a[u] = bfs(w[16 * g + 2 * u + PR]);
  *(b16x8*)(base + 1024) = a;
  *(f32x4*)(base + 2048) = ((const f32x4*)(sb1 + l * HID))[g];
  *(f32x4*)(base + 3072) = ((const f32x4*)(tb1 + l * HID))[g];

#pragma unroll
  for (int to = 0; to < 2; ++to) {
    const int m = 8 * (c >> 2) + 4 * to + (c & 3);
    const int d = 2 * m + PW;
    b16x8 as = {0, 0, 0, 0, 0, 0, 0, 0}, at = {0, 0, 0, 0, 0, 0, 0, 0};
    const float* w2 = sW2 + (l * LAT + d) * HID + 4 * g;
#pragma unroll
    for (int j = 0; j < 4; ++j) as[j] = bfs(TWO_LOG2E * w2[j]);   // prescaled
    w2 = tW2 + (l * LAT + d) * HID + 4 * g;
#pragma unroll
    for (int j = 0; j < 4; ++j) at[4 + j] = bfs(w2[j]);
    *(b16x8*)(base + 4096 + to * 1024) = as;
    *(b16x8*)(base + 6144 + to * 1024) = at;
    f32x4 cs, ct;
#pragma unroll
    for (int j = 0; j < 4; ++j) {
      cs[j] = TWO_LOG2E * sb2[l * LAT + 16 * g + 8 * to + 2 * j + PW];  // prescaled
      ct[j] = tb2[l * LAT + 16 * g + 8 * to + 2 * j + PW];
    }
    *(f32x4*)(base + 8192 + to * 1024) = cs;
    *(f32x4*)(base + 10240 + to * 1024) = ct;
  }
}

// ---------------- main: one coupling layer ----------------
// zst[T][p][uh][j] = z[row=rowbase+16T+c][dim = 16g + 2*(4uh+j) + p]  (f32)
// zbf[T][p] = same 8 values bf16-packed = B-operand of GEMM1 (k=8g+u).
// ds prescaled by 2*log2(e); r = 1/(exp2(ds)+1); ld = 512-2*sum(r).
// Reciprocals computed 4-at-a-time: 1 v_rcp + 9 v_mul replace 4 v_rcp.
template<int PR>
__device__ __forceinline__ void layer_step(
    const char* __restrict__ b0,
    f32x4 (&zst)[2][2][2], b16x8 (&zbf)[2][2], float (&rsum)[2][2])
{
  constexpr int PW = 1 - PR;
  // sub-bases so every load uses a 13-bit immediate offset (<=3072)
  const char* b1 = b0 + 4096;
  const char* b2 = b0 + 8192;
  const b16x8 a1s  = *(const b16x8*)(b0);
  const b16x8 a1t  = *(const b16x8*)(b0 + 1024);
  const f32x4 b1s  = *(const f32x4*)(b0 + 2048);
  const f32x4 b1t  = *(const f32x4*)(b0 + 3072);
  const b16x8 a2s0 = *(const b16x8*)(b1);
  const b16x8 a2s1 = *(const b16x8*)(b1 + 1024);
  const b16x8 a2t0 = *(const b16x8*)(b1 + 2048);
  const b16x8 a2t1 = *(const b16x8*)(b1 + 3072);
  const f32x4 c2s0 = *(const f32x4*)(b2);
  const f32x4 c2s1 = *(const f32x4*)(b2 + 1024);
  const f32x4 c2t0 = *(const f32x4*)(b2 + 2048);
  const f32x4 c2t1 = *(const f32x4*)(b2 + 3072);

#pragma unroll
  for (int T = 0; T < 2; ++T) {
    const f32x4 hs = MFMA32(a1s, zbf[T][PR], b1s);
    const f32x4 ht = MFMA32(a1t, zbf[T][PR], b1t);
    union { unsigned u[4]; b16x8 v; } hc;   // [LeakyReLU(Hs) | LeakyReLU(Ht)]
    hc.u[0] = pk2(leaky(hs[0]), leaky(hs[1]));
    hc.u[1] = pk2(leaky(hs[2]), leaky(hs[3]));
    hc.u[2] = pk2(leaky(ht[0]), leaky(ht[1]));
    hc.u[3] = pk2(leaky(ht[2]), leaky(ht[3]));
    const f32x4 ds0 = MFMA32(a2s0, hc.v, c2s0);
    const f32x4 dt0 = MFMA32(a2t0, hc.v, c2t0);
    const f32x4 ds1 = MFMA32(a2s1, hc.v, c2s1);
    const f32x4 dt1 = MFMA32(a2t1, hc.v, c2t1);
    f32x4 z0 = zst[T][PW][0], z1 = zst[T][PW][1];

    // a_j = exp2(min(ds,25)) + 1  (clamp: tanh saturated anyway; keeps the
    // 4-product <= 2^100, no overflow). Batched reciprocal, exact to ~5e-7.
    f32x4 a0v, a1v;
#pragma unroll
    for (int j = 0; j < 4; ++j) {
      a0v[j] = fexp2(fminf(ds0[j], 25.f)) + 1.f;
      a1v[j] = fexp2(fminf(ds1[j], 25.f)) + 1.f;
    }
    const float m01a = a0v[0] * a0v[1], m23a = a0v[2] * a0v[3];
    const float Ra = frcp(m01a * m23a);
    const float R01a = Ra * m23a, R23a = Ra * m01a;
    const f32x4 r0v = {R01a * a0v[1], R01a * a0v[0], R23a * a0v[3], R23a * a0v[2]};
    const float m01b = a1v[0] * a1v[1], m23b = a1v[2] * a1v[3];
    const float Rb = frcp(m01b * m23b);
    const float R01b = Rb * m23b, R23b = Rb * m01b;
    const f32x4 r1v = {R01b * a1v[1], R01b * a1v[0], R23b * a1v[3], R23b * a1v[2]};

#pragma unroll
    for (int j = 0; j < 4; ++j) {
      rsum[T][0] += r0v[j];
      z0[j] = fmaf(z0[j], fexp2(fmaf(-TWO_LOG2E, r0v[j], LOG2E)), dt0[j]);
      rsum[T][1] += r1v[j];
      z1[j] = fmaf(z1[j], fexp2(fmaf(-TWO_LOG2E, r1v[j], LOG2E)), dt1[j]);
    }
    zst[T][PW][0] = z0;
    zst[T][PW][1] = z1;
    union { unsigned u[4]; b16x8 v; } nz;
    nz.u[0] = pk2(z0[0], z0[1]);
    nz.u[1] = pk2(z0[2], z0[3]);
    nz.u[2] = pk2(z1[0], z1[1]);
    nz.u[3] = pk2(z1[2], z1[3]);
    zbf[T][PW] = nz.v;
  }
}

__global__ __launch_bounds__(64) void realnvp_fwd(
    const float* __restrict__ x, float* __restrict__ out,
    const char* __restrict__ ws)
{
  const int lane = threadIdx.x;          // 0..63
  const int c = lane & 15, g = lane >> 4;
  const int rowbase = blockIdx.x * 32;   // 32 rows per wave (T=2 x 16)

  f32x4 zst[2][2][2];
  b16x8 zbf[2][2];
  float rsum[2][2] = {{0.f, 0.f}, {0.f, 0.f}};
#pragma unroll
  for (int T = 0; T < 2; ++T) {
    const f32x4* xr = (const f32x4*)(x + (size_t)(rowbase + T * 16 + c) * LAT);
    const f32x4 q0 = xr[4 * g], q1 = xr[4 * g + 1], q2 = xr[4 * g + 2], q3 = xr[4 * g + 3];
    zst[T][0][0] = (f32x4){q0[0], q0[2], q1[0], q1[2]};
    zst[T][1][0] = (f32x4){q0[1], q0[3], q1[1], q1[3]};
    zst[T][0][1] = (f32x4){q2[0], q2[2], q3[0], q3[2]};
    zst[T][1][1] = (f32x4){q2[1], q2[3], q3[1], q3[3]};
#pragma unroll
    for (int p = 0; p < 2; ++p) {
      union { unsigned u[4]; b16x8 v; } zb;
      zb.u[0] = pk2(zst[T][p][0][0], zst[T][p][0][1]);
      zb.u[1] = pk2(zst[T][p][0][2], zst[T][p][0][3]);
      zb.u[2] = pk2(zst[T][p][1][0], zst[T][p][1][1]);
      zb.u[3] = pk2(zst[T][p][1][2], zst[T][p][1][3]);
      zbf[T][p] = zb.v;
    }
  }

  const char* b0 = ws + lane * 16;
#pragma unroll 1
  for (int lp = 0; lp < NL / 2; ++lp) {
    layer_step<0>(b0, zst, zbf, rsum);
    layer_step<1>(b0 + LSTRIDE, zst, zbf, rsum);
    b0 += 2 * LSTRIDE;
  }

#pragma unroll
  for (int T = 0; T < 2; ++T) {
    f32x4* zo = (f32x4*)(out + (size_t)(rowbase + T * 16 + c) * LAT);
    const f32x4 e0 = zst[T][0][0], o0 = zst[T][1][0];
    const f32x4 e1 = zst[T][0][1], o1 = zst[T][1][1];
    zo[4 * g]     = (f32x4){e0[0], o0[0], e0[1], o0[1]};
    zo[4 * g + 1] = (f32x4){e0[2], o0[2], e0[3], o0[3]};
    zo[4 * g + 2] = (f32x4){e1[0], o1[0], e1[1], o1[1]};
    zo[4 * g + 3] = (f32x4){e1[2], o1[2], e1[3], o1[3]};
  }
  // ld = sum(1-2r) over 512 tanh terms per row = 512 - 2*sum(r)
  float ldv[2];
#pragma unroll
  for (int T = 0; T < 2; ++T) {
    float rs = rsum[T][0] + rsum[T][1];
    rs += __shfl_xor(rs, 16, 64);
    rs += __shfl_xor(rs, 32, 64);
    ldv[T] = fmaf(-2.f, rs, 512.f);
  }
  if (g < 2)
    out[(size_t)BATCHN * LAT + rowbase + g * 16 + c] = g ? ldv[1] : ldv[0];
}

extern "C" void kernel_launch(void* const* d_in, const int* in_sizes, int n_in,
                              void* d_out, int out_size, void* d_ws, size_t ws_size,
                              hipStream_t stream) {
  const float* x   = (const float*)d_in[0];
  const float* sW1 = (const float*)d_in[1];
  const float* sb1 = (const float*)d_in[2];
  const float* sW2 = (const float*)d_in[3];
  const float* sb2 = (const float*)d_in[4];
  const float* tW1 = (const float*)d_in[5];
  const float* tb1 = (const float*)d_in[6];
  const float* tW2 = (const float*)d_in[7];
  const float* tb2 = (const float*)d_in[8];
  float* out = (float*)d_out;
  char* ws = (char*)d_ws;   // NL * 12288 = 192 KiB

  hipLaunchKernelGGL(prep_frags, dim3(NL), dim3(64), 0, stream,
                     sW1, sb1, sW2, sb2, tW1, tb1, tW2, tb2, ws);
  hipLaunchKernelGGL(realnvp_fwd, dim3(BATCHN / 32), dim3(64), 0, stream,
                     x, out, ws);
}